// Round 6
// baseline (332.927 us; speedup 1.0000x reference)
//
#include <hip/hip_runtime.h>

// LIF scan: mem = 0.25*mem + x[t]; spk = (mem >= 1); mem -= spk.
// x: [T=100, 32, 16384] f32. Parallel over N=524288 neurons, sequential in T.
// Memory-bound. Kernel est ~98us (~4.3 TB/s); harness fixed overhead ~230us
// (800MiB ws poison fill + 210MB out fill + 210MB in restore).
//
// History: R1 float4/8w/4deep=338 | R3 float2/16w/10deep=334 | R4 float1/32w=345
//          | R5 = R3+nontemporal=328. Parallelism-insensitive -> memory-system
// pattern limited. R6: float4 (16B/lane, 1KB/wave-inst -> half the request
// count of R5) + nt + CH=8 window. Tests the request-size/scatter lever.

constexpr int T = 100;
constexpr int N = 32 * 16384;      // 524288 neurons
constexpr int NV4 = N / 4;         // 131072 float4 columns
constexpr int CH = 4;              // t-steps per chunk; 2 windows => 8 in flight

typedef float v4f __attribute__((ext_vector_type(4)));  // builtin-compatible float4

__global__ __launch_bounds__(256) void lif_kernel(const v4f* __restrict__ x,
                                                  v4f* __restrict__ out) {
    const int i = blockIdx.x * 256 + threadIdx.x;   // float4 column index
    const v4f* xp = x + i;
    v4f* op = out + i;

    v4f mem = {0.f, 0.f, 0.f, 0.f};

    for (int c = 0; c < T; c += 2 * CH) {          // 12.5 -> T=100 is 12*8+4: handle tail
        v4f xs[2 * CH];
        const int nleft = T - c;                   // 8 except last chunk (4)
        const int nn = nleft < 2 * CH ? nleft : 2 * CH;
#pragma unroll
        for (int k = 0; k < 2 * CH; ++k)           // up to 8 independent nt loads
            if (k < nn)
                xs[k] = __builtin_nontemporal_load(xp + (size_t)(c + k) * NV4);

#pragma unroll
        for (int k = 0; k < 2 * CH; ++k) {
            if (k >= nn) break;
            const v4f xt = xs[k];
            v4f s;
            // __fmul_rn/__fadd_rn: match numpy's separate mul+add bit-exactly
            // (no FMA contraction) — hard threshold makes ulp drift cascade.
            mem.x = __fadd_rn(__fmul_rn(0.25f, mem.x), xt.x);
            mem.y = __fadd_rn(__fmul_rn(0.25f, mem.y), xt.y);
            mem.z = __fadd_rn(__fmul_rn(0.25f, mem.z), xt.z);
            mem.w = __fadd_rn(__fmul_rn(0.25f, mem.w), xt.w);
            s.x = (mem.x >= 1.0f) ? 1.0f : 0.0f;
            s.y = (mem.y >= 1.0f) ? 1.0f : 0.0f;
            s.z = (mem.z >= 1.0f) ? 1.0f : 0.0f;
            s.w = (mem.w >= 1.0f) ? 1.0f : 0.0f;
            mem.x -= s.x;
            mem.y -= s.y;
            mem.z -= s.z;
            mem.w -= s.w;
            __builtin_nontemporal_store(s, op + (size_t)(c + k) * NV4);
        }
    }
}

extern "C" void kernel_launch(void* const* d_in, const int* in_sizes, int n_in,
                              void* d_out, int out_size, void* d_ws, size_t ws_size,
                              hipStream_t stream) {
    const v4f* x = (const v4f*)d_in[0];
    v4f* out = (v4f*)d_out;
    const int blocks = NV4 / 256;   // 512 -> 2 blocks/CU, 8 waves/CU
    lif_kernel<<<blocks, 256, 0, stream>>>(x, out);
}